// Round 5
// baseline (829.789 us; speedup 1.0000x reference)
//
#include <hip/hip_runtime.h>
#include <cstdint>

#define H 1024
#define F 2048
#define E_N 8
#define BM 128
#define BK 64

typedef __attribute__((ext_vector_type(8))) short short8v;
typedef __attribute__((ext_vector_type(4))) float float4v;
typedef unsigned short u16;

__device__ __forceinline__ u16 f2bf(float f) {
    uint32_t u = __float_as_uint(f);
    u += 0x7FFFu + ((u >> 16) & 1u);   // round-to-nearest-even
    return (u16)(u >> 16);
}
__device__ __forceinline__ float bf2f(u16 b) {
    return __uint_as_float(((uint32_t)b) << 16);
}

__device__ __forceinline__ void gload16(const void* g, void* l) {
    __builtin_amdgcn_global_load_lds((const __attribute__((address_space(1))) uint32_t*)g,
                                     (__attribute__((address_space(3))) uint32_t*)l, 16, 0, 0);
}

// bijective XCD chunk swizzle (m204) + tile-mid / gy-inner order
__device__ __forceinline__ void decode_swz(int bid, int nTiles, int ngy, int gyc,
                                           int& tile, int& gy) {
    int nblk = nTiles * ngy;
    int q = nblk >> 3, r = nblk & 7;
    int xcd = bid & 7, pos = bid >> 3;
    int cid = (xcd < r ? xcd * (q + 1) : r * (q + 1) + (xcd - r) * q) + pos;
    int per = nTiles * gyc;
    int chunk = cid / per, rem = cid - chunk * per;
    tile = rem / gyc;
    gy = chunk * gyc + (rem - (rem / gyc) * gyc);
}

// ---------------- fp32 -> bf16 (weights and x) ----------------
__global__ __launch_bounds__(256) void cvt_kernel(const float* __restrict__ src,
                                                  u16* __restrict__ dst, int n) {
    int i = (blockIdx.x * 256 + threadIdx.x) * 4;
    int stride = gridDim.x * 256 * 4;
    for (; i < n; i += stride) {
        float4 v = *(const float4*)(src + i);
        ushort4 o;
        o.x = f2bf(v.x); o.y = f2bf(v.y); o.z = f2bf(v.z); o.w = f2bf(v.w);
        *(ushort4*)(dst + i) = o;
    }
}

// ---------------- router (no atomics) ----------------
__global__ __launch_bounds__(256) void router_kernel(const float* __restrict__ x,
                                                     const float* __restrict__ gw,
                                                     int* __restrict__ topi,
                                                     float* __restrict__ topw, int T) {
    int wave = threadIdx.x >> 6, lane = threadIdx.x & 63;
    int t = blockIdx.x * 4 + wave;
    if (t >= T) return;
    const float4* xr = (const float4*)(x + (size_t)t * H);
    float4 xv[4];
#pragma unroll
    for (int i = 0; i < 4; i++) xv[i] = xr[i * 64 + lane];
    float acc[E_N];
#pragma unroll
    for (int e = 0; e < E_N; e++) {
        const float4* gr = (const float4*)(gw + e * H);
        float s = 0.f;
#pragma unroll
        for (int i = 0; i < 4; i++) {
            float4 g = gr[i * 64 + lane];
            s += xv[i].x * g.x + xv[i].y * g.y + xv[i].z * g.z + xv[i].w * g.w;
        }
        acc[e] = s;
    }
#pragma unroll
    for (int e = 0; e < E_N; e++) {
#pragma unroll
        for (int off = 32; off; off >>= 1) acc[e] += __shfl_xor(acc[e], off, 64);
    }
    if (lane == 0) {
        int i0 = 0;
#pragma unroll
        for (int e = 1; e < E_N; e++) if (acc[e] > acc[i0]) i0 = e;
        int i1 = -1;
#pragma unroll
        for (int e = 0; e < E_N; e++) {
            if (e == i0) continue;
            if (i1 < 0 || acc[e] > acc[i1]) i1 = e;
        }
        float e1 = __expf(acc[i1] - acc[i0]);
        float w0 = 1.f / (1.f + e1);
        float w1v = e1 / (1.f + e1);
        topi[t * 2] = i0; topi[t * 2 + 1] = i1;
        topw[t * 2] = w0; topw[t * 2 + 1] = w1v;
    }
}

// ---------------- histogram: 8 global atomics per block ----------------
__global__ __launch_bounds__(256) void hist_kernel(const int* __restrict__ topi,
                                                   int* __restrict__ counts, int n) {
    __shared__ int hc[E_N];
    if (threadIdx.x < E_N) hc[threadIdx.x] = 0;
    __syncthreads();
    for (int i = blockIdx.x * 256 + threadIdx.x; i < n; i += gridDim.x * 256)
        atomicAdd(&hc[topi[i]], 1);
    __syncthreads();
    if (threadIdx.x < E_N) atomicAdd(&counts[threadIdx.x], hc[threadIdx.x]);
}

// ---------------- tiny serial scan ----------------
__global__ void scan_kernel(const int* __restrict__ counts, int* __restrict__ offsets,
                            int* __restrict__ cursors, int* __restrict__ tileOff) {
    if (threadIdx.x == 0 && blockIdx.x == 0) {
        int o = 0, to = 0;
        for (int e = 0; e < E_N; e++) {
            offsets[e] = o; cursors[e] = o; tileOff[e] = to;
            o += counts[e];
            to += (counts[e] + BM - 1) / BM;
        }
        offsets[E_N] = o; tileOff[E_N] = to;
    }
}

// ---------------- scatter: block-local ranks, 8 global atomics per block ----------------
__global__ __launch_bounds__(1024) void scatter_kernel(const int* __restrict__ topi,
                                                       const float* __restrict__ topw,
                                                       int* __restrict__ cursors,
                                                       int* __restrict__ perm_tok,
                                                       float* __restrict__ perm_gate,
                                                       int* __restrict__ inv, int n) {
    __shared__ int hc[E_N];
    __shared__ int base[E_N];
    int tid = threadIdx.x;
    if (tid < E_N) hc[tid] = 0;
    __syncthreads();
    int i = blockIdx.x * 1024 + tid;
    int e = 0, lrank = 0;
    bool ok = (i < n);
    if (ok) {
        e = topi[i];
        lrank = atomicAdd(&hc[e], 1);
    }
    __syncthreads();
    if (tid < E_N) base[tid] = atomicAdd(&cursors[tid], hc[tid]);
    __syncthreads();
    if (ok) {
        int pos = base[e] + lrank;
        perm_tok[pos] = i >> 1;
        perm_gate[pos] = topw[i];
        inv[i] = pos;
    }
}

// ---------------- stage 1: h = gate * silu(xg@w1^T) * (xg@w3^T) ----------------
// 2-phase double-buffered: STAGE(t+1) -> MFMA(t) -> vmcnt(0)+barrier
__global__ __launch_bounds__(256) void stage1_kernel(
    const u16* __restrict__ xg, const u16* __restrict__ w1b, const u16* __restrict__ w3b,
    const int* __restrict__ perm_tok, const float* __restrict__ perm_gate,
    const int* __restrict__ offsets, const int* __restrict__ tileOff,
    u16* __restrict__ h, int cstart, int tpcThis) {
    __shared__ u16 lA[2][BM * BK];
    __shared__ u16 lB1[2][64 * BK];
    __shared__ u16 lB3[2][64 * BK];
    __shared__ int ptokS[BM];
    __shared__ float pgateS[BM];

    int tileL, nbIdx;
    decode_swz(blockIdx.x, tpcThis, F / 64, 4, tileL, nbIdx);
    int tile = cstart + tileL;
    if (tile >= tileOff[E_N]) return;
    int e = 0;
    while (e < E_N - 1 && tile >= tileOff[e + 1]) e++;
    int rbase = offsets[e] + (tile - tileOff[e]) * BM;
    int segEnd = offsets[e + 1];
    int e0 = 0;
    while (e0 < E_N - 1 && cstart >= tileOff[e0 + 1]) e0++;
    int chunkBase = offsets[e0] + (cstart - tileOff[e0]) * BM;

    int tid = threadIdx.x;
    if (tid < BM) {
        int p = rbase + tid; if (p > segEnd - 1) p = segEnd - 1;
        ptokS[tid] = perm_tok[p];
        pgateS[tid] = perm_gate[p];
    }
    __syncthreads();

    int lane = tid & 63, wave = tid >> 6;
    int mBase = (wave >> 1) * 64, nBaseW = (wave & 1) * 32;
    int lrow = lane & 15, kgrp = lane >> 4;
    int nb = nbIdx * 64;
    const u16* w1p = w1b + (size_t)e * F * H + (size_t)nb * H;
    const u16* w3p = w3b + (size_t)e * F * H + (size_t)nb * H;

    // swizzled-source staging: LDS[r][c8] = G[r][c8 ^ (r&7)] (8-elem units)
    int lr = lane >> 3;
    int csw = ((lane & 7) ^ lr) << 3;

    const u16* aSrc[4];
#pragma unroll
    for (int j = 0; j < 4; j++) {
        int rb = (j * 4 + wave) * 8;
        int tok = ptokS[rb + lr];
        aSrc[j] = xg + (size_t)tok * H + csw;
    }
    const u16 *b1Src[2], *b3Src[2];
#pragma unroll
    for (int j = 0; j < 2; j++) {
        int rr = (j * 4 + wave) * 8 + lr;
        b1Src[j] = w1p + (size_t)rr * H + csw;
        b3Src[j] = w3p + (size_t)rr * H + csw;
    }

    auto stage = [&](int kt, int b) {
        int ko = kt * BK;
#pragma unroll
        for (int j = 0; j < 4; j++)
            gload16(aSrc[j] + ko, &lA[b][((j * 4 + wave) * 8) * BK]);
#pragma unroll
        for (int j = 0; j < 2; j++) {
            int rb = (j * 4 + wave) * 8;
            gload16(b1Src[j] + ko, &lB1[b][rb * BK]);
            gload16(b3Src[j] + ko, &lB3[b][rb * BK]);
        }
    };

    float4v acc1[4][2], acc3[4][2];
#pragma unroll
    for (int a = 0; a < 4; a++)
#pragma unroll
        for (int b = 0; b < 2; b++) { acc1[a][b] = (float4v)(0.f); acc3[a][b] = (float4v)(0.f); }

    stage(0, 0);
    asm volatile("s_waitcnt vmcnt(0)" ::: "memory");
    __syncthreads();

    for (int kt = 0; kt < H / BK; kt++) {
        int cur = kt & 1;
        if (kt + 1 < H / BK) stage(kt + 1, cur ^ 1);
#pragma unroll
        for (int kk = 0; kk < 2; kk++) {
            int kg = kk * 4 + kgrp;
            short8v aF[4], b1F[2], b3F[2];
#pragma unroll
            for (int fm = 0; fm < 4; fm++) {
                int r = mBase + fm * 16 + lrow;
                aF[fm] = *(const short8v*)&lA[cur][r * BK + ((kg ^ (r & 7)) << 3)];
            }
#pragma unroll
            for (int fn = 0; fn < 2; fn++) {
                int c = nBaseW + fn * 16 + lrow;
                b1F[fn] = *(const short8v*)&lB1[cur][c * BK + ((kg ^ (c & 7)) << 3)];
                b3F[fn] = *(const short8v*)&lB3[cur][c * BK + ((kg ^ (c & 7)) << 3)];
            }
#pragma unroll
            for (int fm = 0; fm < 4; fm++)
#pragma unroll
                for (int fn = 0; fn < 2; fn++) {
                    acc1[fm][fn] = __builtin_amdgcn_mfma_f32_16x16x32_bf16(aF[fm], b1F[fn], acc1[fm][fn], 0, 0, 0);
                    acc3[fm][fn] = __builtin_amdgcn_mfma_f32_16x16x32_bf16(aF[fm], b3F[fn], acc3[fm][fn], 0, 0, 0);
                }
        }
        asm volatile("s_waitcnt vmcnt(0)" ::: "memory");
        __syncthreads();
    }
    int rif = (lane >> 4) * 4;
#pragma unroll
    for (int fm = 0; fm < 4; fm++) {
#pragma unroll
        for (int reg = 0; reg < 4; reg++) {
            int rowIdx = mBase + fm * 16 + rif + reg;
            int p = rbase + rowIdx;
            if (p < segEnd) {
                float g = pgateS[rowIdx];
#pragma unroll
                for (int fn = 0; fn < 2; fn++) {
                    float a1 = acc1[fm][fn][reg], a3 = acc3[fm][fn][reg];
                    float sv = a1 / (1.f + __expf(-a1));
                    float hv = sv * a3 * g;
                    int ncol = nb + nBaseW + fn * 16 + (lane & 15);
                    h[(size_t)(p - chunkBase) * F + ncol] = f2bf(hv);
                }
            }
        }
    }
}

// ---------------- stage 2: y[p] = h[p] @ w2^T (bf16 out, written once) ----------------
__global__ __launch_bounds__(256) void stage2_kernel(
    const u16* __restrict__ h, const u16* __restrict__ w2b,
    const int* __restrict__ offsets, const int* __restrict__ tileOff,
    u16* __restrict__ y, int cstart, int tpcThis) {
    __shared__ u16 lA[2][BM * BK];
    __shared__ u16 lB[2][BM * BK];

    int tileL, nbIdx;
    decode_swz(blockIdx.x, tpcThis, H / 128, 4, tileL, nbIdx);
    int tile = cstart + tileL;
    if (tile >= tileOff[E_N]) return;
    int e = 0;
    while (e < E_N - 1 && tile >= tileOff[e + 1]) e++;
    int rbase = offsets[e] + (tile - tileOff[e]) * BM;
    int segEnd = offsets[e + 1];
    int e0 = 0;
    while (e0 < E_N - 1 && cstart >= tileOff[e0 + 1]) e0++;
    int chunkBase = offsets[e0] + (cstart - tileOff[e0]) * BM;

    int tid = threadIdx.x;
    int lane = tid & 63, wave = tid >> 6;
    int mBase = (wave >> 1) * 64, nBaseW = (wave & 1) * 64;
    int lrow = lane & 15, kgrp = lane >> 4;
    int nb = nbIdx * 128;
    const u16* w2p = w2b + (size_t)e * H * F + (size_t)nb * F;

    int lr = lane >> 3;
    int csw = ((lane & 7) ^ lr) << 3;

    const u16 *aSrc[4], *bSrc[4];
#pragma unroll
    for (int j = 0; j < 4; j++) {
        int rb = (j * 4 + wave) * 8;
        int p = rbase + rb + lr; if (p > segEnd - 1) p = segEnd - 1;
        aSrc[j] = h + (size_t)(p - chunkBase) * F + csw;
        int rr = rb + lr;
        bSrc[j] = w2p + (size_t)rr * F + csw;
    }

    auto stage = [&](int kt, int b) {
        int ko = kt * BK;
#pragma unroll
        for (int j = 0; j < 4; j++) {
            int rb = (j * 4 + wave) * 8;
            gload16(aSrc[j] + ko, &lA[b][rb * BK]);
            gload16(bSrc[j] + ko, &lB[b][rb * BK]);
        }
    };

    float4v acc[4][4];
#pragma unroll
    for (int a = 0; a < 4; a++)
#pragma unroll
        for (int b = 0; b < 4; b++) acc[a][b] = (float4v)(0.f);

    stage(0, 0);
    asm volatile("s_waitcnt vmcnt(0)" ::: "memory");
    __syncthreads();

    for (int kt = 0; kt < F / BK; kt++) {
        int cur = kt & 1;
        if (kt + 1 < F / BK) stage(kt + 1, cur ^ 1);
#pragma unroll
        for (int kk = 0; kk < 2; kk++) {
            int kg = kk * 4 + kgrp;
            short8v aF[4], bF[4];
#pragma unroll
            for (int fm = 0; fm < 4; fm++) {
                int r = mBase + fm * 16 + lrow;
                aF[fm] = *(const short8v*)&lA[cur][r * BK + ((kg ^ (r & 7)) << 3)];
            }
#pragma unroll
            for (int fn = 0; fn < 4; fn++) {
                int c = nBaseW + fn * 16 + lrow;
                bF[fn] = *(const short8v*)&lB[cur][c * BK + ((kg ^ (c & 7)) << 3)];
            }
#pragma unroll
            for (int fm = 0; fm < 4; fm++)
#pragma unroll
                for (int fn = 0; fn < 4; fn++)
                    acc[fm][fn] = __builtin_amdgcn_mfma_f32_16x16x32_bf16(aF[fm], bF[fn], acc[fm][fn], 0, 0, 0);
        }
        asm volatile("s_waitcnt vmcnt(0)" ::: "memory");
        __syncthreads();
    }
    int rif = (lane >> 4) * 4;
#pragma unroll
    for (int fm = 0; fm < 4; fm++) {
#pragma unroll
        for (int reg = 0; reg < 4; reg++) {
            int rowIdx = mBase + fm * 16 + rif + reg;
            int p = rbase + rowIdx;
            if (p < segEnd) {
#pragma unroll
                for (int fn = 0; fn < 4; fn++) {
                    int n = nb + nBaseW + fn * 16 + (lane & 15);
                    y[(size_t)p * H + n] = f2bf(acc[fm][fn][reg]);
                }
            }
        }
    }
}

// ---------------- combine: out[t] = y[slot0] + y[slot1] ----------------
__global__ __launch_bounds__(256) void combine_kernel(const u16* __restrict__ y,
                                                      const int* __restrict__ inv,
                                                      float* __restrict__ out) {
    int t = blockIdx.x, c = threadIdx.x;  // 256 threads x 4 floats = H
    int s0 = inv[t * 2], s1 = inv[t * 2 + 1];
    ushort4 a = *(const ushort4*)(y + (size_t)s0 * H + c * 4);
    ushort4 b = *(const ushort4*)(y + (size_t)s1 * H + c * 4);
    float4 o;
    o.x = bf2f(a.x) + bf2f(b.x);
    o.y = bf2f(a.y) + bf2f(b.y);
    o.z = bf2f(a.z) + bf2f(b.z);
    o.w = bf2f(a.w) + bf2f(b.w);
    *(float4*)(out + (size_t)t * H + c * 4) = o;
}

extern "C" void kernel_launch(void* const* d_in, const int* in_sizes, int n_in,
                              void* d_out, int out_size, void* d_ws, size_t ws_size,
                              hipStream_t stream) {
    (void)n_in; (void)out_size;
    const float* x  = (const float*)d_in[0];
    const float* gw = (const float*)d_in[1];
    const float* w1 = (const float*)d_in[2];
    const float* w2 = (const float*)d_in[3];
    const float* w3 = (const float*)d_in[4];
    float* out = (float*)d_out;
    int T = in_sizes[0] / H;   // 16384
    int P = T * 2;

    char* ws = (char*)d_ws;
    size_t off = 0;
    auto alloc = [&](size_t b) { size_t c = off; off = (off + b + 255) & ~(size_t)255; return c; };
    size_t misc_o  = alloc(256);
    int* counts  = (int*)(ws + misc_o);
    int* offsets = (int*)(ws + misc_o + 64);
    int* cursors = (int*)(ws + misc_o + 128);
    int* tileOff = (int*)(ws + misc_o + 192);
    size_t topi_o  = alloc((size_t)T * 2 * 4);
    size_t topw_o  = alloc((size_t)T * 2 * 4);
    size_t ptok_o  = alloc((size_t)P * 4);
    size_t pgate_o = alloc((size_t)P * 4);
    size_t inv_o   = alloc((size_t)T * 2 * 4);
    size_t w1b_o = alloc((size_t)E_N * F * H * 2);
    size_t w3b_o = alloc((size_t)E_N * F * H * 2);
    size_t w2b_o = alloc((size_t)E_N * H * F * 2);
    size_t xg_o  = alloc((size_t)T * H * 2);     // token-order bf16 x
    size_t y_o   = alloc((size_t)P * H * 2);     // bf16 per-slot output

    // h buffer: sized by the ACTUAL remaining workspace (no overflow possible)
    int maxTiles = P / BM + E_N;  // 264
    size_t perTile = (size_t)BM * F * 2;  // 512 KB
    size_t avail = (ws_size > off + 256) ? (ws_size - off - 256) : 0;
    int tpc = (int)(avail / perTile);
    if (tpc > maxTiles) tpc = maxTiles;
    if (tpc < 8) tpc = 8;  // absolute floor (4 MB)
    size_t h_o = alloc((size_t)tpc * perTile);

    hipMemsetAsync(ws + misc_o, 0, 256, stream);

    int nW = E_N * F * H;
    cvt_kernel<<<4096, 256, 0, stream>>>(w1, (u16*)(ws + w1b_o), nW);
    cvt_kernel<<<4096, 256, 0, stream>>>(w3, (u16*)(ws + w3b_o), nW);
    cvt_kernel<<<4096, 256, 0, stream>>>(w2, (u16*)(ws + w2b_o), nW);
    cvt_kernel<<<4096, 256, 0, stream>>>(x,  (u16*)(ws + xg_o),  T * H);

    router_kernel<<<T / 4, 256, 0, stream>>>(x, gw, (int*)(ws + topi_o), (float*)(ws + topw_o), T);
    hist_kernel<<<32, 256, 0, stream>>>((int*)(ws + topi_o), counts, P);
    scan_kernel<<<1, 64, 0, stream>>>(counts, offsets, cursors, tileOff);
    scatter_kernel<<<(P + 1023) / 1024, 1024, 0, stream>>>(
        (int*)(ws + topi_o), (float*)(ws + topw_o), cursors,
        (int*)(ws + ptok_o), (float*)(ws + pgate_o), (int*)(ws + inv_o), P);

    for (int cstart = 0; cstart < maxTiles; cstart += tpc) {
        int tpcThis = maxTiles - cstart; if (tpcThis > tpc) tpcThis = tpc;
        stage1_kernel<<<tpcThis * (F / 64), 256, 0, stream>>>(
            (u16*)(ws + xg_o), (u16*)(ws + w1b_o), (u16*)(ws + w3b_o),
            (int*)(ws + ptok_o), (float*)(ws + pgate_o), offsets, tileOff,
            (u16*)(ws + h_o), cstart, tpcThis);
        stage2_kernel<<<tpcThis * (H / 128), 256, 0, stream>>>(
            (u16*)(ws + h_o), (u16*)(ws + w2b_o), offsets, tileOff,
            (u16*)(ws + y_o), cstart, tpcThis);
    }
    combine_kernel<<<T, 256, 0, stream>>>((u16*)(ws + y_o), (int*)(ws + inv_o), out);
}

// Round 6
// 688.788 us; speedup vs baseline: 1.2047x; 1.2047x over previous
//
#include <hip/hip_runtime.h>
#include <cstdint>

#define H 1024
#define F 2048
#define E_N 8
#define BM 256
#define BK 64

typedef __attribute__((ext_vector_type(8))) short short8v;
typedef __attribute__((ext_vector_type(4))) float float4v;
typedef unsigned short u16;

__device__ __forceinline__ u16 f2bf(float f) {
    uint32_t u = __float_as_uint(f);
    u += 0x7FFFu + ((u >> 16) & 1u);   // round-to-nearest-even
    return (u16)(u >> 16);
}
__device__ __forceinline__ float bf2f(u16 b) {
    return __uint_as_float(((uint32_t)b) << 16);
}

__device__ __forceinline__ void gload16(const void* g, void* l) {
    __builtin_amdgcn_global_load_lds((const __attribute__((address_space(1))) uint32_t*)g,
                                     (__attribute__((address_space(3))) uint32_t*)l, 16, 0, 0);
}

// raw barrier (no vmcnt drain) with compiler memory fence
__device__ __forceinline__ void barx() {
    asm volatile("" ::: "memory");
    __builtin_amdgcn_s_barrier();
    asm volatile("" ::: "memory");
}

// bijective XCD chunk swizzle (m204) + tile-mid / gy-inner order
__device__ __forceinline__ void decode_swz(int bid, int nTiles, int ngy, int gyc,
                                           int& tile, int& gy) {
    int nblk = nTiles * ngy;
    int q = nblk >> 3, r = nblk & 7;
    int xcd = bid & 7, pos = bid >> 3;
    int cid = (xcd < r ? xcd * (q + 1) : r * (q + 1) + (xcd - r) * q) + pos;
    int per = nTiles * gyc;
    int chunk = cid / per, rem = cid - chunk * per;
    tile = rem / gyc;
    gy = chunk * gyc + (rem - (rem / gyc) * gyc);
}

// ---------------- fp32 -> bf16 (weights and x) ----------------
__global__ __launch_bounds__(256) void cvt_kernel(const float* __restrict__ src,
                                                  u16* __restrict__ dst, int n) {
    int i = (blockIdx.x * 256 + threadIdx.x) * 4;
    int stride = gridDim.x * 256 * 4;
    for (; i < n; i += stride) {
        float4 v = *(const float4*)(src + i);
        ushort4 o;
        o.x = f2bf(v.x); o.y = f2bf(v.y); o.z = f2bf(v.z); o.w = f2bf(v.w);
        *(ushort4*)(dst + i) = o;
    }
}

// ---------------- router (no atomics) ----------------
__global__ __launch_bounds__(256) void router_kernel(const float* __restrict__ x,
                                                     const float* __restrict__ gw,
                                                     int* __restrict__ topi,
                                                     float* __restrict__ topw, int T) {
    int wave = threadIdx.x >> 6, lane = threadIdx.x & 63;
    int t = blockIdx.x * 4 + wave;
    if (t >= T) return;
    const float4* xr = (const float4*)(x + (size_t)t * H);
    float4 xv[4];
#pragma unroll
    for (int i = 0; i < 4; i++) xv[i] = xr[i * 64 + lane];
    float acc[E_N];
#pragma unroll
    for (int e = 0; e < E_N; e++) {
        const float4* gr = (const float4*)(gw + e * H);
        float s = 0.f;
#pragma unroll
        for (int i = 0; i < 4; i++) {
            float4 g = gr[i * 64 + lane];
            s += xv[i].x * g.x + xv[i].y * g.y + xv[i].z * g.z + xv[i].w * g.w;
        }
        acc[e] = s;
    }
#pragma unroll
    for (int e = 0; e < E_N; e++) {
#pragma unroll
        for (int off = 32; off; off >>= 1) acc[e] += __shfl_xor(acc[e], off, 64);
    }
    if (lane == 0) {
        int i0 = 0;
#pragma unroll
        for (int e = 1; e < E_N; e++) if (acc[e] > acc[i0]) i0 = e;
        int i1 = -1;
#pragma unroll
        for (int e = 0; e < E_N; e++) {
            if (e == i0) continue;
            if (i1 < 0 || acc[e] > acc[i1]) i1 = e;
        }
        float e1 = __expf(acc[i1] - acc[i0]);
        float w0 = 1.f / (1.f + e1);
        float w1v = e1 / (1.f + e1);
        topi[t * 2] = i0; topi[t * 2 + 1] = i1;
        topw[t * 2] = w0; topw[t * 2 + 1] = w1v;
    }
}

// ---------------- histogram: 8 global atomics per block ----------------
__global__ __launch_bounds__(256) void hist_kernel(const int* __restrict__ topi,
                                                   int* __restrict__ counts, int n) {
    __shared__ int hc[E_N];
    if (threadIdx.x < E_N) hc[threadIdx.x] = 0;
    __syncthreads();
    for (int i = blockIdx.x * 256 + threadIdx.x; i < n; i += gridDim.x * 256)
        atomicAdd(&hc[topi[i]], 1);
    __syncthreads();
    if (threadIdx.x < E_N) atomicAdd(&counts[threadIdx.x], hc[threadIdx.x]);
}

// ---------------- tiny serial scan ----------------
__global__ void scan_kernel(const int* __restrict__ counts, int* __restrict__ offsets,
                            int* __restrict__ cursors, int* __restrict__ tileOff) {
    if (threadIdx.x == 0 && blockIdx.x == 0) {
        int o = 0, to = 0;
        for (int e = 0; e < E_N; e++) {
            offsets[e] = o; cursors[e] = o; tileOff[e] = to;
            o += counts[e];
            to += (counts[e] + BM - 1) / BM;
        }
        offsets[E_N] = o; tileOff[E_N] = to;
    }
}

// ---------------- scatter: block-local ranks, 8 global atomics per block ----------------
__global__ __launch_bounds__(1024) void scatter_kernel(const int* __restrict__ topi,
                                                       const float* __restrict__ topw,
                                                       int* __restrict__ cursors,
                                                       int* __restrict__ perm_tok,
                                                       float* __restrict__ perm_gate,
                                                       int* __restrict__ inv, int n) {
    __shared__ int hc[E_N];
    __shared__ int base[E_N];
    int tid = threadIdx.x;
    if (tid < E_N) hc[tid] = 0;
    __syncthreads();
    int i = blockIdx.x * 1024 + tid;
    int e = 0, lrank = 0;
    bool ok = (i < n);
    if (ok) {
        e = topi[i];
        lrank = atomicAdd(&hc[e], 1);
    }
    __syncthreads();
    if (tid < E_N) base[tid] = atomicAdd(&cursors[tid], hc[tid]);
    __syncthreads();
    if (ok) {
        int pos = base[e] + lrank;
        perm_tok[pos] = i >> 1;
        perm_gate[pos] = topw[i];
        inv[i] = pos;
    }
}

// ---------------- stage 1: h = gate * silu(xg@w1^T) * (xg@w3^T) ----------------
// 256-row tile, BN=128 (dual w1/w3), 8 waves, 4-phase counted-vmcnt schedule
__global__ __launch_bounds__(512) void stage1_kernel(
    const u16* __restrict__ xg, const u16* __restrict__ w1b, const u16* __restrict__ w3b,
    const int* __restrict__ perm_tok, const float* __restrict__ perm_gate,
    const int* __restrict__ offsets, const int* __restrict__ tileOff,
    u16* __restrict__ h, int cstart, int tpcThis) {
    __shared__ u16 lA[2][BM * BK];      // 64 KB
    __shared__ u16 lB1[2][128 * BK];    // 32 KB
    __shared__ u16 lB3[2][128 * BK];    // 32 KB
    __shared__ int ptokS[BM];
    __shared__ float pgateS[BM];

    int tileL, nbIdx;
    decode_swz(blockIdx.x, tpcThis, F / 128, 4, tileL, nbIdx);
    int tile = cstart + tileL;
    if (tile >= tileOff[E_N]) return;
    int e = 0;
    while (e < E_N - 1 && tile >= tileOff[e + 1]) e++;
    int rbase = offsets[e] + (tile - tileOff[e]) * BM;
    int segEnd = offsets[e + 1];
    int e0 = 0;
    while (e0 < E_N - 1 && cstart >= tileOff[e0 + 1]) e0++;
    int chunkBase = offsets[e0] + (cstart - tileOff[e0]) * BM;

    int tid = threadIdx.x;
    if (tid < BM) {
        int p = rbase + tid; if (p > segEnd - 1) p = segEnd - 1;
        ptokS[tid] = perm_tok[p];
        pgateS[tid] = perm_gate[p];
    }
    __syncthreads();

    int lane = tid & 63, wid = tid >> 6;
    int wr = wid >> 2, wc = wid & 3;
    int lrow = lane & 15, kgrp = lane >> 4;
    int lr = lane >> 3, csw = ((lane & 7) ^ lr) << 3;
    int nb = nbIdx * 128;
    const u16* w1p = w1b + (size_t)e * F * H + (size_t)nb * H;
    const u16* w3p = w3b + (size_t)e * F * H + (size_t)nb * H;

    int aOff[4];
#pragma unroll
    for (int j = 0; j < 4; j++) {
        int rb = (j * 8 + wid) * 8;
        aOff[j] = ptokS[rb + lr] * H + csw;
    }
    int bOff[2];
#pragma unroll
    for (int j = 0; j < 2; j++) bOff[j] = ((j * 8 + wid) * 8 + lr) * H + csw;

    auto stA  = [&](int cc, int ko, int j) { gload16(xg  + aOff[j] + ko, &lA[cc][(j * 8 + wid) * 8 * BK]); };
    auto stB1 = [&](int cc, int ko, int j) { gload16(w1p + bOff[j] + ko, &lB1[cc][(j * 8 + wid) * 8 * BK]); };
    auto stB3 = [&](int cc, int ko, int j) { gload16(w3p + bOff[j] + ko, &lB3[cc][(j * 8 + wid) * 8 * BK]); };

    float4v acc1[8][2], acc3[8][2];
#pragma unroll
    for (int a = 0; a < 8; a++)
#pragma unroll
        for (int b = 0; b < 2; b++) { acc1[a][b] = (float4v)(0.f); acc3[a][b] = (float4v)(0.f); }

    // prologue: tile 0 (order: B1, B3, A-half0 (j0,j2), A-half1 (j1,j3))
    stB1(0, 0, 0); stB1(0, 0, 1);
    stB3(0, 0, 0); stB3(0, 0, 1);
    stA(0, 0, 0);  stA(0, 0, 2);
    stA(0, 0, 1);  stA(0, 0, 3);
    asm volatile("s_waitcnt vmcnt(2)" ::: "memory");   // allow A-half1 in flight
    barx();

#define S1_DS(p) \
    short8v aF##p[2][2]; \
    _Pragma("unroll") \
    for (int pm = 0; pm < 2; pm++) { \
        int r = wr * 128 + (2 * p + pm) * 16 + lrow; \
        _Pragma("unroll") \
        for (int kk = 0; kk < 2; kk++) \
            aF##p[pm][kk] = *(const short8v*)&Ac[r * BK + (((kk * 4 + kgrp) ^ (r & 7)) << 3)]; \
    }
#define S1_MM(p) \
    __builtin_amdgcn_s_setprio(1); \
    _Pragma("unroll") \
    for (int pm = 0; pm < 2; pm++) \
    _Pragma("unroll") \
    for (int n = 0; n < 2; n++) \
    _Pragma("unroll") \
    for (int kk = 0; kk < 2; kk++) { \
        acc1[2 * p + pm][n] = __builtin_amdgcn_mfma_f32_16x16x32_bf16(aF##p[pm][kk], b1F[n][kk], acc1[2 * p + pm][n], 0, 0, 0); \
        acc3[2 * p + pm][n] = __builtin_amdgcn_mfma_f32_16x16x32_bf16(aF##p[pm][kk], b3F[n][kk], acc3[2 * p + pm][n], 0, 0, 0); \
    } \
    __builtin_amdgcn_s_setprio(0);

    const int NT = H / BK;  // 16
    for (int t = 0; t < NT; t++) {
        int c = t & 1, cN = c ^ 1;
        int ko = (t + 1) * BK;
        bool pf = (t + 1 < NT);
        const u16* Ac = lA[c]; const u16* B1c = lB1[c]; const u16* B3c = lB3[c];
        short8v b1F[2][2], b3F[2][2];
#pragma unroll
        for (int n = 0; n < 2; n++) {
            int col = wc * 32 + n * 16 + lrow;
#pragma unroll
            for (int kk = 0; kk < 2; kk++) {
                int so = col * BK + (((kk * 4 + kgrp) ^ (col & 7)) << 3);
                b1F[n][kk] = *(const short8v*)&B1c[so];
                b3F[n][kk] = *(const short8v*)&B3c[so];
            }
        }
        // phase 0 (reads A rows +0..31; A-half1 of this tile may still be in flight)
        S1_DS(0)
        if (pf) { stB1(cN, ko, 0); stB1(cN, ko, 1); }
        barx();
        S1_MM(0)
        barx();
        // phase 1
        S1_DS(1)
        if (pf) { stB3(cN, ko, 0); stB3(cN, ko, 1); }
        barx();
        S1_MM(1)
        if (pf) asm volatile("s_waitcnt vmcnt(4)" ::: "memory");  // this tile's A-half1 landed
        else    asm volatile("s_waitcnt vmcnt(0)" ::: "memory");
        barx();
        // phase 2
        S1_DS(2)
        if (pf) { stA(cN, ko, 0); stA(cN, ko, 2); }
        barx();
        S1_MM(2)
        barx();
        // phase 3
        S1_DS(3)
        if (pf) { stA(cN, ko, 1); stA(cN, ko, 3); }
        barx();
        S1_MM(3)
        asm volatile("s_waitcnt vmcnt(2)" ::: "memory");  // next tile's B+A-half0 landed
        barx();
    }
#undef S1_DS
#undef S1_MM

    int rif = (lane >> 4) * 4;
#pragma unroll
    for (int m = 0; m < 8; m++) {
#pragma unroll
        for (int reg = 0; reg < 4; reg++) {
            int rowIdx = wr * 128 + m * 16 + rif + reg;
            int p = rbase + rowIdx;
            if (p < segEnd) {
                float g = pgateS[rowIdx];
#pragma unroll
                for (int n = 0; n < 2; n++) {
                    float a1 = acc1[m][n][reg], a3 = acc3[m][n][reg];
                    float sv = a1 / (1.f + __expf(-a1));
                    float hv = sv * a3 * g;
                    int ncol = nb + wc * 32 + n * 16 + (lane & 15);
                    h[(size_t)(p - chunkBase) * F + ncol] = f2bf(hv);
                }
            }
        }
    }
}

// ---------------- stage 2: y[p] = h[p] @ w2^T ----------------
// 256-row tile, BN = NREP*64, 8 waves, 4-phase counted-vmcnt schedule
template<int NREP>
__global__ __launch_bounds__(512) void stage2_kernel(
    const u16* __restrict__ h, const u16* __restrict__ w2b,
    const int* __restrict__ offsets, const int* __restrict__ tileOff,
    u16* __restrict__ y, int cstart, int tpcThis) {
    constexpr int BN = NREP * 64;
    __shared__ u16 lA[2][BM * BK];
    __shared__ u16 lB[2][BN * BK];

    int tileL, nbIdx;
    decode_swz(blockIdx.x, tpcThis, H / BN, 4, tileL, nbIdx);
    int tile = cstart + tileL;
    if (tile >= tileOff[E_N]) return;
    int e = 0;
    while (e < E_N - 1 && tile >= tileOff[e + 1]) e++;
    int rbase = offsets[e] + (tile - tileOff[e]) * BM;
    int segEnd = offsets[e + 1];
    int e0 = 0;
    while (e0 < E_N - 1 && cstart >= tileOff[e0 + 1]) e0++;
    int chunkBase = offsets[e0] + (cstart - tileOff[e0]) * BM;

    int tid = threadIdx.x;
    int lane = tid & 63, wid = tid >> 6;
    int wr = wid >> 2, wc = wid & 3;
    int lrow = lane & 15, kgrp = lane >> 4;
    int lr = lane >> 3, csw = ((lane & 7) ^ lr) << 3;
    int nb = nbIdx * BN;
    const u16* w2p = w2b + (size_t)e * H * F + (size_t)nb * F;

    int aOff[4];
#pragma unroll
    for (int j = 0; j < 4; j++) {
        int rb = (j * 8 + wid) * 8;
        int p = rbase + rb + lr; if (p > segEnd - 1) p = segEnd - 1;
        aOff[j] = (p - chunkBase) * F + csw;
    }
    int bOff[NREP];
#pragma unroll
    for (int j = 0; j < NREP; j++) bOff[j] = ((j * 8 + wid) * 8 + lr) * F + csw;

    auto stA = [&](int cc, int ko, int j) { gload16(h   + aOff[j] + ko, &lA[cc][(j * 8 + wid) * 8 * BK]); };
    auto stB = [&](int cc, int ko, int j) { gload16(w2p + bOff[j] + ko, &lB[cc][(j * 8 + wid) * 8 * BK]); };

    float4v acc[8][NREP];
#pragma unroll
    for (int a = 0; a < 8; a++)
#pragma unroll
        for (int b = 0; b < NREP; b++) acc[a][b] = (float4v)(0.f);

    // prologue: tile 0 (B all, A-half0 (j0,j2), A-half1 (j1,j3))
#pragma unroll
    for (int j = 0; j < NREP; j++) stB(0, 0, j);
    stA(0, 0, 0); stA(0, 0, 2);
    stA(0, 0, 1); stA(0, 0, 3);
    asm volatile("s_waitcnt vmcnt(2)" ::: "memory");
    barx();

#define S2_DS(p) \
    short8v aF##p[2][2]; \
    _Pragma("unroll") \
    for (int pm = 0; pm < 2; pm++) { \
        int r = wr * 128 + (2 * p + pm) * 16 + lrow; \
        _Pragma("unroll") \
        for (int kk = 0; kk < 2; kk++) \
            aF##p[pm][kk] = *(const short8v*)&Ac[r * BK + (((kk * 4 + kgrp) ^ (r & 7)) << 3)]; \
    }
#define S2_MM(p) \
    __builtin_amdgcn_s_setprio(1); \
    _Pragma("unroll") \
    for (int pm = 0; pm < 2; pm++) \
    _Pragma("unroll") \
    for (int n = 0; n < NREP; n++) \
    _Pragma("unroll") \
    for (int kk = 0; kk < 2; kk++) \
        acc[2 * p + pm][n] = __builtin_amdgcn_mfma_f32_16x16x32_bf16(aF##p[pm][kk], bF[n][kk], acc[2 * p + pm][n], 0, 0, 0); \
    __builtin_amdgcn_s_setprio(0);

    const int NT = F / BK;  // 32
    for (int t = 0; t < NT; t++) {
        int c = t & 1, cN = c ^ 1;
        int ko = (t + 1) * BK;
        bool pf = (t + 1 < NT);
        const u16* Ac = lA[c]; const u16* Bc = lB[c];
        short8v bF[NREP][2];
#pragma unroll
        for (int n = 0; n < NREP; n++) {
            int col = wc * (BN / 4) + n * 16 + lrow;
#pragma unroll
            for (int kk = 0; kk < 2; kk++)
                bF[n][kk] = *(const short8v*)&Bc[col * BK + (((kk * 4 + kgrp) ^ (col & 7)) << 3)];
        }
        // phase 0
        S2_DS(0)
        if (pf) { stB(cN, ko, 0); if constexpr (NREP == 4) stB(cN, ko, 1); }
        barx();
        S2_MM(0)
        barx();
        // phase 1
        S2_DS(1)
        if (pf) {
            if constexpr (NREP == 4) { stB(cN, ko, 2); stB(cN, ko, 3); }
            else stB(cN, ko, 1);
        }
        barx();
        S2_MM(1)
        if (pf) {
            if constexpr (NREP == 4) asm volatile("s_waitcnt vmcnt(4)" ::: "memory");
            else                     asm volatile("s_waitcnt vmcnt(2)" ::: "memory");
        } else {
            asm volatile("s_waitcnt vmcnt(0)" ::: "memory");
        }
        barx();
        // phase 2
        S2_DS(2)
        if (pf) { stA(cN, ko, 0); stA(cN, ko, 2); }
        barx();
        S2_MM(2)
        barx();
        // phase 3
        S2_DS(3)
        if (pf) { stA(cN, ko, 1); stA(cN, ko, 3); }
        barx();
        S2_MM(3)
        asm volatile("s_waitcnt vmcnt(2)" ::: "memory");
        barx();
    }
#undef S2_DS
#undef S2_MM

    int rif = (lane >> 4) * 4;
#pragma unroll
    for (int m = 0; m < 8; m++) {
#pragma unroll
        for (int reg = 0; reg < 4; reg++) {
            int rowIdx = wr * 128 + m * 16 + rif + reg;
            int p = rbase + rowIdx;
            if (p < segEnd) {
#pragma unroll
                for (int n = 0; n < NREP; n++) {
                    int col = nb + wc * (BN / 4) + n * 16 + (lane & 15);
                    y[(size_t)p * H + col] = f2bf(acc[m][n][reg]);
                }
            }
        }
    }
}

// ---------------- combine: out[t] = y[slot0] + y[slot1] ----------------
__global__ __launch_bounds__(256) void combine_kernel(const u16* __restrict__ y,
                                                      const int* __restrict__ inv,
                                                      float* __restrict__ out) {
    int t = blockIdx.x, c = threadIdx.x;
    int s0 = inv[t * 2], s1 = inv[t * 2 + 1];
    ushort4 a = *(const ushort4*)(y + (size_t)s0 * H + c * 4);
    ushort4 b = *(const ushort4*)(y + (size_t)s1 * H + c * 4);
    float4 o;
    o.x = bf2f(a.x) + bf2f(b.x);
    o.y = bf2f(a.y) + bf2f(b.y);
    o.z = bf2f(a.z) + bf2f(b.z);
    o.w = bf2f(a.w) + bf2f(b.w);
    *(float4*)(out + (size_t)t * H + c * 4) = o;
}

extern "C" void kernel_launch(void* const* d_in, const int* in_sizes, int n_in,
                              void* d_out, int out_size, void* d_ws, size_t ws_size,
                              hipStream_t stream) {
    (void)n_in; (void)out_size;
    const float* x  = (const float*)d_in[0];
    const float* gw = (const float*)d_in[1];
    const float* w1 = (const float*)d_in[2];
    const float* w2 = (const float*)d_in[3];
    const float* w3 = (const float*)d_in[4];
    float* out = (float*)d_out;
    int T = in_sizes[0] / H;   // 16384
    int P = T * 2;

    char* ws = (char*)d_ws;
    size_t off = 0;
    auto alloc = [&](size_t b) { size_t c = off; off = (off + b + 255) & ~(size_t)255; return c; };
    size_t misc_o  = alloc(256);
    int* counts  = (int*)(ws + misc_o);
    int* offsets = (int*)(ws + misc_o + 64);
    int* cursors = (int*)(ws + misc_o + 128);
    int* tileOff = (int*)(ws + misc_o + 192);
    size_t topi_o  = alloc((size_t)T * 2 * 4);
    size_t topw_o  = alloc((size_t)T * 2 * 4);
    size_t ptok_o  = alloc((size_t)P * 4);
    size_t pgate_o = alloc((size_t)P * 4);
    size_t inv_o   = alloc((size_t)T * 2 * 4);
    size_t w1b_o = alloc((size_t)E_N * F * H * 2);
    size_t w3b_o = alloc((size_t)E_N * F * H * 2);
    size_t w2b_o = alloc((size_t)E_N * H * F * 2);
    size_t xg_o  = alloc((size_t)T * H * 2);     // token-order bf16 x
    size_t y_o   = alloc((size_t)P * H * 2);     // bf16 per-slot output

    // h buffer sized from the ACTUAL remaining workspace
    int maxTiles = P / BM + E_N;            // 136
    size_t perTile = (size_t)BM * F * 2;    // 1 MB
    size_t avail = (ws_size > off + 256) ? (ws_size - off - 256) : 0;
    int tpc = (int)(avail / perTile);
    if (tpc > maxTiles) tpc = maxTiles;
    if (tpc < 4) tpc = 4;
    size_t h_o = alloc((size_t)tpc * perTile);

    hipMemsetAsync(ws + misc_o, 0, 256, stream);

    int nW = E_N * F * H;
    cvt_kernel<<<4096, 256, 0, stream>>>(w1, (u16*)(ws + w1b_o), nW);
    cvt_kernel<<<4096, 256, 0, stream>>>(w3, (u16*)(ws + w3b_o), nW);
    cvt_kernel<<<4096, 256, 0, stream>>>(w2, (u16*)(ws + w2b_o), nW);
    cvt_kernel<<<4096, 256, 0, stream>>>(x,  (u16*)(ws + xg_o),  T * H);

    router_kernel<<<T / 4, 256, 0, stream>>>(x, gw, (int*)(ws + topi_o), (float*)(ws + topw_o), T);
    hist_kernel<<<32, 256, 0, stream>>>((int*)(ws + topi_o), counts, P);
    scan_kernel<<<1, 64, 0, stream>>>(counts, offsets, cursors, tileOff);
    scatter_kernel<<<(P + 1023) / 1024, 1024, 0, stream>>>(
        (int*)(ws + topi_o), (float*)(ws + topw_o), cursors,
        (int*)(ws + ptok_o), (float*)(ws + pgate_o), (int*)(ws + inv_o), P);

    for (int cstart = 0; cstart < maxTiles; cstart += tpc) {
        int tpcThis = maxTiles - cstart; if (tpcThis > tpc) tpcThis = tpc;
        stage1_kernel<<<tpcThis * (F / 128), 512, 0, stream>>>(
            (u16*)(ws + xg_o), (u16*)(ws + w1b_o), (u16*)(ws + w3b_o),
            (int*)(ws + ptok_o), (float*)(ws + pgate_o), offsets, tileOff,
            (u16*)(ws + h_o), cstart, tpcThis);
        if (tpcThis >= 54)
            stage2_kernel<4><<<tpcThis * (H / 256), 512, 0, stream>>>(
                (u16*)(ws + h_o), (u16*)(ws + w2b_o), offsets, tileOff,
                (u16*)(ws + y_o), cstart, tpcThis);
        else
            stage2_kernel<2><<<tpcThis * (H / 128), 512, 0, stream>>>(
                (u16*)(ws + h_o), (u16*)(ws + w2b_o), offsets, tileOff,
                (u16*)(ws + y_o), cstart, tpcThis);
    }
    combine_kernel<<<T, 256, 0, stream>>>((u16*)(ws + y_o), (int*)(ws + inv_o), out);
}

// Round 7
// 640.042 us; speedup vs baseline: 1.2965x; 1.0762x over previous
//
#include <hip/hip_runtime.h>
#include <cstdint>

#define H 1024
#define F 2048
#define E_N 8
#define BM 256
#define BK 64

typedef __attribute__((ext_vector_type(8))) short short8v;
typedef __attribute__((ext_vector_type(4))) float float4v;
typedef unsigned short u16;

__device__ __forceinline__ u16 f2bf(float f) {
    uint32_t u = __float_as_uint(f);
    u += 0x7FFFu + ((u >> 16) & 1u);   // round-to-nearest-even
    return (u16)(u >> 16);
}
__device__ __forceinline__ float bf2f(u16 b) {
    return __uint_as_float(((uint32_t)b) << 16);
}

__device__ __forceinline__ void gload16(const void* g, void* l) {
    __builtin_amdgcn_global_load_lds((const __attribute__((address_space(1))) uint32_t*)g,
                                     (__attribute__((address_space(3))) uint32_t*)l, 16, 0, 0);
}

// raw barrier (no vmcnt drain) with compiler memory fence
__device__ __forceinline__ void barx() {
    asm volatile("" ::: "memory");
    __builtin_amdgcn_s_barrier();
    asm volatile("" ::: "memory");
}

// bijective XCD chunk swizzle (m204) + tile-mid / gy-inner order
__device__ __forceinline__ void decode_swz(int bid, int nTiles, int ngy, int gyc,
                                           int& tile, int& gy) {
    int nblk = nTiles * ngy;
    int q = nblk >> 3, r = nblk & 7;
    int xcd = bid & 7, pos = bid >> 3;
    int cid = (xcd < r ? xcd * (q + 1) : r * (q + 1) + (xcd - r) * q) + pos;
    int per = nTiles * gyc;
    int chunk = cid / per, rem = cid - chunk * per;
    tile = rem / gyc;
    gy = chunk * gyc + (rem - (rem / gyc) * gyc);
}

// ---------------- fp32 -> bf16 (weights and x) ----------------
__global__ __launch_bounds__(256) void cvt_kernel(const float* __restrict__ src,
                                                  u16* __restrict__ dst, int n) {
    int i = (blockIdx.x * 256 + threadIdx.x) * 4;
    int stride = gridDim.x * 256 * 4;
    for (; i < n; i += stride) {
        float4 v = *(const float4*)(src + i);
        ushort4 o;
        o.x = f2bf(v.x); o.y = f2bf(v.y); o.z = f2bf(v.z); o.w = f2bf(v.w);
        *(ushort4*)(dst + i) = o;
    }
}

// ---------------- router (no atomics) ----------------
__global__ __launch_bounds__(256) void router_kernel(const float* __restrict__ x,
                                                     const float* __restrict__ gw,
                                                     int* __restrict__ topi,
                                                     float* __restrict__ topw, int T) {
    int wave = threadIdx.x >> 6, lane = threadIdx.x & 63;
    int t = blockIdx.x * 4 + wave;
    if (t >= T) return;
    const float4* xr = (const float4*)(x + (size_t)t * H);
    float4 xv[4];
#pragma unroll
    for (int i = 0; i < 4; i++) xv[i] = xr[i * 64 + lane];
    float acc[E_N];
#pragma unroll
    for (int e = 0; e < E_N; e++) {
        const float4* gr = (const float4*)(gw + e * H);
        float s = 0.f;
#pragma unroll
        for (int i = 0; i < 4; i++) {
            float4 g = gr[i * 64 + lane];
            s += xv[i].x * g.x + xv[i].y * g.y + xv[i].z * g.z + xv[i].w * g.w;
        }
        acc[e] = s;
    }
#pragma unroll
    for (int e = 0; e < E_N; e++) {
#pragma unroll
        for (int off = 32; off; off >>= 1) acc[e] += __shfl_xor(acc[e], off, 64);
    }
    if (lane == 0) {
        int i0 = 0;
#pragma unroll
        for (int e = 1; e < E_N; e++) if (acc[e] > acc[i0]) i0 = e;
        int i1 = -1;
#pragma unroll
        for (int e = 0; e < E_N; e++) {
            if (e == i0) continue;
            if (i1 < 0 || acc[e] > acc[i1]) i1 = e;
        }
        float e1 = __expf(acc[i1] - acc[i0]);
        float w0 = 1.f / (1.f + e1);
        float w1v = e1 / (1.f + e1);
        topi[t * 2] = i0; topi[t * 2 + 1] = i1;
        topw[t * 2] = w0; topw[t * 2 + 1] = w1v;
    }
}

// ---------------- histogram: 8 global atomics per block ----------------
__global__ __launch_bounds__(256) void hist_kernel(const int* __restrict__ topi,
                                                   int* __restrict__ counts, int n) {
    __shared__ int hc[E_N];
    if (threadIdx.x < E_N) hc[threadIdx.x] = 0;
    __syncthreads();
    for (int i = blockIdx.x * 256 + threadIdx.x; i < n; i += gridDim.x * 256)
        atomicAdd(&hc[topi[i]], 1);
    __syncthreads();
    if (threadIdx.x < E_N) atomicAdd(&counts[threadIdx.x], hc[threadIdx.x]);
}

// ---------------- tiny serial scan ----------------
__global__ void scan_kernel(const int* __restrict__ counts, int* __restrict__ offsets,
                            int* __restrict__ cursors, int* __restrict__ tileOff) {
    if (threadIdx.x == 0 && blockIdx.x == 0) {
        int o = 0, to = 0;
        for (int e = 0; e < E_N; e++) {
            offsets[e] = o; cursors[e] = o; tileOff[e] = to;
            o += counts[e];
            to += (counts[e] + BM - 1) / BM;
        }
        offsets[E_N] = o; tileOff[E_N] = to;
    }
}

// ---------------- scatter: block-local ranks, 8 global atomics per block ----------------
__global__ __launch_bounds__(1024) void scatter_kernel(const int* __restrict__ topi,
                                                       const float* __restrict__ topw,
                                                       int* __restrict__ cursors,
                                                       int* __restrict__ perm_tok,
                                                       float* __restrict__ perm_gate,
                                                       int* __restrict__ inv, int n) {
    __shared__ int hc[E_N];
    __shared__ int base[E_N];
    int tid = threadIdx.x;
    if (tid < E_N) hc[tid] = 0;
    __syncthreads();
    int i = blockIdx.x * 1024 + tid;
    int e = 0, lrank = 0;
    bool ok = (i < n);
    if (ok) {
        e = topi[i];
        lrank = atomicAdd(&hc[e], 1);
    }
    __syncthreads();
    if (tid < E_N) base[tid] = atomicAdd(&cursors[tid], hc[tid]);
    __syncthreads();
    if (ok) {
        int pos = base[e] + lrank;
        perm_tok[pos] = i >> 1;
        perm_gate[pos] = topw[i];
        inv[i] = pos;
    }
}

// ---------------- stage 1: h = gate * silu(xg@w1^T) * (xg@w3^T) ----------------
// 256-row tile, BN=128 (dual w1/w3), 8 waves, 4-phase counted-vmcnt schedule.
// All ds_read addresses are hoisted per-thread bases + compile-time immediates.
__global__ __launch_bounds__(512) void stage1_kernel(
    const u16* __restrict__ xg, const u16* __restrict__ w1b, const u16* __restrict__ w3b,
    const int* __restrict__ perm_tok, const float* __restrict__ perm_gate,
    const int* __restrict__ offsets, const int* __restrict__ tileOff,
    u16* __restrict__ h, int cstart, int tpcThis) {
    __shared__ u16 lA[2 * BM * BK];      // 64 KB, buf stride 16384 elems
    __shared__ u16 lB1[2 * 128 * BK];    // 32 KB, buf stride 8192
    __shared__ u16 lB3[2 * 128 * BK];    // 32 KB
    __shared__ int ptokS[BM];
    __shared__ float pgateS[BM];

    int tileL, nbIdx;
    decode_swz(blockIdx.x, tpcThis, F / 128, 4, tileL, nbIdx);
    int tile = cstart + tileL;
    if (tile >= tileOff[E_N]) return;
    int e = 0;
    while (e < E_N - 1 && tile >= tileOff[e + 1]) e++;
    int rbase = offsets[e] + (tile - tileOff[e]) * BM;
    int segEnd = offsets[e + 1];
    int e0 = 0;
    while (e0 < E_N - 1 && cstart >= tileOff[e0 + 1]) e0++;
    int chunkBase = offsets[e0] + (cstart - tileOff[e0]) * BM;

    int tid = threadIdx.x;
    if (tid < BM) {
        int p = rbase + tid; if (p > segEnd - 1) p = segEnd - 1;
        ptokS[tid] = perm_tok[p];
        pgateS[tid] = perm_gate[p];
    }
    __syncthreads();

    int lane = tid & 63, wid = tid >> 6;
    int wr = wid >> 2, wc = wid & 3;
    int lrow = lane & 15, kgrp = lane >> 4;
    int lr = lane >> 3, csw = ((lane & 7) ^ lr) << 3;
    int nb = nbIdx * 128;
    const u16* w1p = w1b + (size_t)e * F * H + (size_t)nb * H;
    const u16* w3p = w3b + (size_t)e * F * H + (size_t)nb * H;

    // global stage pointers (swizzled-source; advance +BK per K-tile)
    const u16* pA[4];
#pragma unroll
    for (int j = 0; j < 4; j++) pA[j] = xg + (size_t)ptokS[(j * 8 + wid) * 8 + lr] * H + csw;
    const u16 *pB1[2], *pB3[2];
#pragma unroll
    for (int j = 0; j < 2; j++) {
        int rr = (j * 8 + wid) * 8 + lr;
        pB1[j] = w1p + (size_t)rr * H + csw;
        pB3[j] = w3p + (size_t)rr * H + csw;
    }

    // hoisted ds_read element bases (r&7 == lrow&7 for all fragment rows)
    int swe0 = (kgrp ^ (lrow & 7)) << 3;
    int swe1 = ((4 + kgrp) ^ (lrow & 7)) << 3;
    int eA0 = (wr * 128 + lrow) * BK + swe0;
    int eA1 = (wr * 128 + lrow) * BK + swe1;
    int eB0 = (wc * 32 + lrow) * BK + swe0;
    int eB1 = (wc * 32 + lrow) * BK + swe1;

#define STA(CC, j)  gload16(pA[j],  &lA[(CC) * 16384 + ((j) * 8 + wid) * 8 * BK])
#define STB1(CC, j) gload16(pB1[j], &lB1[(CC) * 8192 + ((j) * 8 + wid) * 8 * BK])
#define STB3(CC, j) gload16(pB3[j], &lB3[(CC) * 8192 + ((j) * 8 + wid) * 8 * BK])

    float4v acc1[8][2], acc3[8][2];
#pragma unroll
    for (int a = 0; a < 8; a++)
#pragma unroll
        for (int b = 0; b < 2; b++) { acc1[a][b] = (float4v)(0.f); acc3[a][b] = (float4v)(0.f); }

    // prologue: tile 0 into buf 0 (order: B1, B3, A j0,j2, A j1,j3)
    STB1(0, 0); STB1(0, 1);
    STB3(0, 0); STB3(0, 1);
    STA(0, 0); STA(0, 2); STA(0, 1); STA(0, 3);
#pragma unroll
    for (int j = 0; j < 4; j++) pA[j] += BK;
    pB1[0] += BK; pB1[1] += BK; pB3[0] += BK; pB3[1] += BK;
    asm volatile("s_waitcnt vmcnt(2)" ::: "memory");   // A j1,j3 may stay in flight
    barx();

#define S1_DSA(CC, p) \
    short8v aF[2][2]; \
    _Pragma("unroll") \
    for (int pm = 0; pm < 2; pm++) { \
        aF[pm][0] = *(const short8v*)&lA[eA0 + (CC) * 16384 + (2 * (p) + pm) * 1024]; \
        aF[pm][1] = *(const short8v*)&lA[eA1 + (CC) * 16384 + (2 * (p) + pm) * 1024]; \
    }
#define S1_MM(p) \
    __builtin_amdgcn_s_setprio(1); \
    _Pragma("unroll") \
    for (int pm = 0; pm < 2; pm++) \
    _Pragma("unroll") \
    for (int n = 0; n < 2; n++) \
    _Pragma("unroll") \
    for (int kk = 0; kk < 2; kk++) { \
        acc1[2 * (p) + pm][n] = __builtin_amdgcn_mfma_f32_16x16x32_bf16(aF[pm][kk], b1F[n][kk], acc1[2 * (p) + pm][n], 0, 0, 0); \
        acc3[2 * (p) + pm][n] = __builtin_amdgcn_mfma_f32_16x16x32_bf16(aF[pm][kk], b3F[n][kk], acc3[2 * (p) + pm][n], 0, 0, 0); \
    } \
    __builtin_amdgcn_s_setprio(0);

#define S1_KT(CC, LAST) { \
    short8v b1F[2][2], b3F[2][2]; \
    _Pragma("unroll") \
    for (int n = 0; n < 2; n++) { \
        b1F[n][0] = *(const short8v*)&lB1[eB0 + (CC) * 8192 + n * 1024]; \
        b1F[n][1] = *(const short8v*)&lB1[eB1 + (CC) * 8192 + n * 1024]; \
        b3F[n][0] = *(const short8v*)&lB3[eB0 + (CC) * 8192 + n * 1024]; \
        b3F[n][1] = *(const short8v*)&lB3[eB1 + (CC) * 8192 + n * 1024]; \
    } \
    { S1_DSA(CC, 0) \
      if (!(LAST)) { STB1((CC) ^ 1, 0); STB1((CC) ^ 1, 1); } \
      barx(); S1_MM(0) barx(); } \
    { S1_DSA(CC, 1) \
      if (!(LAST)) { STB3((CC) ^ 1, 0); STB3((CC) ^ 1, 1); } \
      barx(); S1_MM(1) \
      if (!(LAST)) { asm volatile("s_waitcnt vmcnt(4)" ::: "memory"); } \
      else         { asm volatile("s_waitcnt vmcnt(0)" ::: "memory"); } \
      barx(); } \
    { S1_DSA(CC, 2) \
      if (!(LAST)) { STA((CC) ^ 1, 0); STA((CC) ^ 1, 2); } \
      barx(); S1_MM(2) barx(); } \
    { S1_DSA(CC, 3) \
      if (!(LAST)) { STA((CC) ^ 1, 1); STA((CC) ^ 1, 3); } \
      barx(); S1_MM(3) \
      asm volatile("s_waitcnt vmcnt(2)" ::: "memory"); \
      barx(); } \
    _Pragma("unroll") \
    for (int j = 0; j < 4; j++) pA[j] += BK; \
    pB1[0] += BK; pB1[1] += BK; pB3[0] += BK; pB3[1] += BK; \
}

    // NT = H/BK = 16 K-tiles, unrolled x2 for compile-time buffer index
    for (int tt = 0; tt < (H / BK) - 2; tt += 2) {
        S1_KT(0, false)
        S1_KT(1, false)
    }
    S1_KT(0, false)
    S1_KT(1, true)
#undef S1_DSA
#undef S1_MM
#undef S1_KT
#undef STA
#undef STB1
#undef STB3

    int rif = (lane >> 4) * 4;
#pragma unroll
    for (int m = 0; m < 8; m++) {
#pragma unroll
        for (int reg = 0; reg < 4; reg++) {
            int rowIdx = wr * 128 + m * 16 + rif + reg;
            int p = rbase + rowIdx;
            if (p < segEnd) {
                float g = pgateS[rowIdx];
#pragma unroll
                for (int n = 0; n < 2; n++) {
                    float a1 = acc1[m][n][reg], a3 = acc3[m][n][reg];
                    float sv = a1 / (1.f + __expf(-a1));
                    float hv = sv * a3 * g;
                    int ncol = nb + wc * 32 + n * 16 + (lane & 15);
                    h[(size_t)(p - chunkBase) * F + ncol] = f2bf(hv);
                }
            }
        }
    }
}

// ---------------- stage 2: y[p] = h[p] @ w2^T ----------------
// 256-row tile, BN = NREP*64, 8 waves, 4-phase counted-vmcnt schedule
template<int NREP>
__global__ __launch_bounds__(512) void stage2_kernel(
    const u16* __restrict__ h, const u16* __restrict__ w2b,
    const int* __restrict__ offsets, const int* __restrict__ tileOff,
    u16* __restrict__ y, int cstart, int tpcThis) {
    constexpr int BN = NREP * 64;
    constexpr int BSTRIDE = BN * BK;       // elems per buf
    __shared__ u16 lA[2 * BM * BK];
    __shared__ u16 lB[2 * BSTRIDE];

    int tileL, nbIdx;
    decode_swz(blockIdx.x, tpcThis, H / BN, 4, tileL, nbIdx);
    int tile = cstart + tileL;
    if (tile >= tileOff[E_N]) return;
    int e = 0;
    while (e < E_N - 1 && tile >= tileOff[e + 1]) e++;
    int rbase = offsets[e] + (tile - tileOff[e]) * BM;
    int segEnd = offsets[e + 1];
    int e0 = 0;
    while (e0 < E_N - 1 && cstart >= tileOff[e0 + 1]) e0++;
    int chunkBase = offsets[e0] + (cstart - tileOff[e0]) * BM;

    int tid = threadIdx.x;
    int lane = tid & 63, wid = tid >> 6;
    int wr = wid >> 2, wc = wid & 3;
    int lrow = lane & 15, kgrp = lane >> 4;
    int lr = lane >> 3, csw = ((lane & 7) ^ lr) << 3;
    int nb = nbIdx * BN;
    const u16* w2p = w2b + (size_t)e * H * F + (size_t)nb * F;

    const u16* pA[4];
#pragma unroll
    for (int j = 0; j < 4; j++) {
        int rb = (j * 8 + wid) * 8;
        int p = rbase + rb + lr; if (p > segEnd - 1) p = segEnd - 1;
        pA[j] = h + (size_t)(p - chunkBase) * F + csw;
    }
    const u16* pB[NREP];
#pragma unroll
    for (int j = 0; j < NREP; j++) pB[j] = w2p + (size_t)((j * 8 + wid) * 8 + lr) * F + csw;

    int swe0 = (kgrp ^ (lrow & 7)) << 3;
    int swe1 = ((4 + kgrp) ^ (lrow & 7)) << 3;
    int eA0 = (wr * 128 + lrow) * BK + swe0;
    int eA1 = (wr * 128 + lrow) * BK + swe1;
    int eB0 = (wc * (NREP * 16) + lrow) * BK + swe0;
    int eB1 = (wc * (NREP * 16) + lrow) * BK + swe1;

#define STA2(CC, j) gload16(pA[j], &lA[(CC) * 16384 + ((j) * 8 + wid) * 8 * BK])
#define STB2(CC, j) gload16(pB[j], &lB[(CC) * BSTRIDE + ((j) * 8 + wid) * 8 * BK])

    float4v acc[8][NREP];
#pragma unroll
    for (int a = 0; a < 8; a++)
#pragma unroll
        for (int b = 0; b < NREP; b++) acc[a][b] = (float4v)(0.f);

    // prologue
#pragma unroll
    for (int j = 0; j < NREP; j++) STB2(0, j);
    STA2(0, 0); STA2(0, 2); STA2(0, 1); STA2(0, 3);
#pragma unroll
    for (int j = 0; j < 4; j++) pA[j] += BK;
#pragma unroll
    for (int j = 0; j < NREP; j++) pB[j] += BK;
    asm volatile("s_waitcnt vmcnt(2)" ::: "memory");
    barx();

#define S2_DSA(CC, p) \
    short8v aF[2][2]; \
    _Pragma("unroll") \
    for (int pm = 0; pm < 2; pm++) { \
        aF[pm][0] = *(const short8v*)&lA[eA0 + (CC) * 16384 + (2 * (p) + pm) * 1024]; \
        aF[pm][1] = *(const short8v*)&lA[eA1 + (CC) * 16384 + (2 * (p) + pm) * 1024]; \
    }
#define S2_MM(p) \
    __builtin_amdgcn_s_setprio(1); \
    _Pragma("unroll") \
    for (int pm = 0; pm < 2; pm++) \
    _Pragma("unroll") \
    for (int n = 0; n < NREP; n++) \
    _Pragma("unroll") \
    for (int kk = 0; kk < 2; kk++) \
        acc[2 * (p) + pm][n] = __builtin_amdgcn_mfma_f32_16x16x32_bf16(aF[pm][kk], bF[n][kk], acc[2 * (p) + pm][n], 0, 0, 0); \
    __builtin_amdgcn_s_setprio(0);

#define S2_KT(CC, LAST) { \
    short8v bF[NREP][2]; \
    _Pragma("unroll") \
    for (int n = 0; n < NREP; n++) { \
        bF[n][0] = *(const short8v*)&lB[eB0 + (CC) * BSTRIDE + n * 1024]; \
        bF[n][1] = *(const short8v*)&lB[eB1 + (CC) * BSTRIDE + n * 1024]; \
    } \
    { S2_DSA(CC, 0) \
      if (!(LAST)) { STB2((CC) ^ 1, 0); if (NREP == 4) STB2((CC) ^ 1, 1); } \
      barx(); S2_MM(0) barx(); } \
    { S2_DSA(CC, 1) \
      if (!(LAST)) { if (NREP == 4) { STB2((CC) ^ 1, 2); STB2((CC) ^ 1, 3); } else STB2((CC) ^ 1, 1); } \
      barx(); S2_MM(1) \
      if (!(LAST)) { \
          if (NREP == 4) { asm volatile("s_waitcnt vmcnt(4)" ::: "memory"); } \
          else           { asm volatile("s_waitcnt vmcnt(2)" ::: "memory"); } \
      } else { asm volatile("s_waitcnt vmcnt(0)" ::: "memory"); } \
      barx(); } \
    { S2_DSA(CC, 2) \
      if (!(LAST)) { STA2((CC) ^ 1, 0); STA2((CC) ^ 1, 2); } \
      barx(); S2_MM(2) barx(); } \
    { S2_DSA(CC, 3) \
      if (!(LAST)) { STA2((CC) ^ 1, 1); STA2((CC) ^ 1, 3); } \
      barx(); S2_MM(3) \
      asm volatile("s_waitcnt vmcnt(2)" ::: "memory"); \
      barx(); } \
    _Pragma("unroll") \
    for (int j = 0; j < 4; j++) pA[j] += BK; \
    _Pragma("unroll") \
    for (int j = 0; j < NREP; j++) pB[j] += BK; \
}

    // NT = F/BK = 32 K-tiles, unrolled x2
    for (int tt = 0; tt < (F / BK) - 2; tt += 2) {
        S2_KT(0, false)
        S2_KT(1, false)
    }
    S2_KT(0, false)
    S2_KT(1, true)
#undef S2_DSA
#undef S2_MM
#undef S2_KT
#undef STA2
#undef STB2

    int rif = (lane >> 4) * 4;
#pragma unroll
    for (int m = 0; m < 8; m++) {
#pragma unroll
        for (int reg = 0; reg < 4; reg++) {
            int rowIdx = wr * 128 + m * 16 + rif + reg;
            int p = rbase + rowIdx;
            if (p < segEnd) {
#pragma unroll
                for (int n = 0; n < NREP; n++) {
                    int col = nb + wc * (BN / 4) + n * 16 + (lane & 15);
                    y[(size_t)p * H + col] = f2bf(acc[m][n][reg]);
                }
            }
        }
    }
}

// ---------------- combine: out[t] = y[slot0] + y[slot1] ----------------
__global__ __launch_bounds__(256) void combine_kernel(const u16* __restrict__ y,
                                                      const int* __restrict__ inv,
                                                      float* __restrict__ out) {
    int t = blockIdx.x, c = threadIdx.x;
    int s0 = inv[t * 2], s1 = inv[t * 2 + 1];
    ushort4 a = *(const ushort4*)(y + (size_t)s0 * H + c * 4);
    ushort4 b = *(const ushort4*)(y + (size_t)s1 * H + c * 4);
    float4 o;
    o.x = bf2f(a.x) + bf2f(b.x);
    o.y = bf2f(a.y) + bf2f(b.y);
    o.z = bf2f(a.z) + bf2f(b.z);
    o.w = bf2f(a.w) + bf2f(b.w);
    *(float4*)(out + (size_t)t * H + c * 4) = o;
}

extern "C" void kernel_launch(void* const* d_in, const int* in_sizes, int n_in,
                              void* d_out, int out_size, void* d_ws, size_t ws_size,
                              hipStream_t stream) {
    (void)n_in; (void)out_size;
    const float* x  = (const float*)d_in[0];
    const float* gw = (const float*)d_in[1];
    const float* w1 = (const float*)d_in[2];
    const float* w2 = (const float*)d_in[3];
    const float* w3 = (const float*)d_in[4];
    float* out = (float*)d_out;
    int T = in_sizes[0] / H;   // 16384
    int P = T * 2;

    char* ws = (char*)d_ws;
    size_t off = 0;
    auto alloc = [&](size_t b) { size_t c = off; off = (off + b + 255) & ~(size_t)255; return c; };
    size_t misc_o  = alloc(256);
    int* counts  = (int*)(ws + misc_o);
    int* offsets = (int*)(ws + misc_o + 64);
    int* cursors = (int*)(ws + misc_o + 128);
    int* tileOff = (int*)(ws + misc_o + 192);
    size_t topi_o  = alloc((size_t)T * 2 * 4);
    size_t topw_o  = alloc((size_t)T * 2 * 4);
    size_t ptok_o  = alloc((size_t)P * 4);
    size_t pgate_o = alloc((size_t)P * 4);
    size_t inv_o   = alloc((size_t)T * 2 * 4);
    size_t w1b_o = alloc((size_t)E_N * F * H * 2);
    size_t w3b_o = alloc((size_t)E_N * F * H * 2);
    size_t w2b_o = alloc((size_t)E_N * H * F * 2);
    size_t xg_o  = alloc((size_t)T * H * 2);     // token-order bf16 x
    size_t y_o   = alloc((size_t)P * H * 2);     // bf16 per-slot output

    // h buffer sized from the ACTUAL remaining workspace
    int maxTiles = P / BM + E_N;            // 136
    size_t perTile = (size_t)BM * F * 2;    // 1 MB
    size_t avail = (ws_size > off + 256) ? (ws_size - off - 256) : 0;
    int tpc = (int)(avail / perTile);
    if (tpc > maxTiles) tpc = maxTiles;
    if (tpc < 4) tpc = 4;
    size_t h_o = alloc((size_t)tpc * perTile);

    hipMemsetAsync(ws + misc_o, 0, 256, stream);

    int nW = E_N * F * H;
    cvt_kernel<<<4096, 256, 0, stream>>>(w1, (u16*)(ws + w1b_o), nW);
    cvt_kernel<<<4096, 256, 0, stream>>>(w3, (u16*)(ws + w3b_o), nW);
    cvt_kernel<<<4096, 256, 0, stream>>>(w2, (u16*)(ws + w2b_o), nW);
    cvt_kernel<<<4096, 256, 0, stream>>>(x,  (u16*)(ws + xg_o),  T * H);

    router_kernel<<<T / 4, 256, 0, stream>>>(x, gw, (int*)(ws + topi_o), (float*)(ws + topw_o), T);
    hist_kernel<<<32, 256, 0, stream>>>((int*)(ws + topi_o), counts, P);
    scan_kernel<<<1, 64, 0, stream>>>(counts, offsets, cursors, tileOff);
    scatter_kernel<<<(P + 1023) / 1024, 1024, 0, stream>>>(
        (int*)(ws + topi_o), (float*)(ws + topw_o), cursors,
        (int*)(ws + ptok_o), (float*)(ws + pgate_o), (int*)(ws + inv_o), P);

    for (int cstart = 0; cstart < maxTiles; cstart += tpc) {
        int tpcThis = maxTiles - cstart; if (tpcThis > tpc) tpcThis = tpc;
        stage1_kernel<<<tpcThis * (F / 128), 512, 0, stream>>>(
            (u16*)(ws + xg_o), (u16*)(ws + w1b_o), (u16*)(ws + w3b_o),
            (int*)(ws + ptok_o), (float*)(ws + pgate_o), offsets, tileOff,
            (u16*)(ws + h_o), cstart, tpcThis);
        if (tpcThis >= 54)
            stage2_kernel<4><<<tpcThis * (H / 256), 512, 0, stream>>>(
                (u16*)(ws + h_o), (u16*)(ws + w2b_o), offsets, tileOff,
                (u16*)(ws + y_o), cstart, tpcThis);
        else
            stage2_kernel<2><<<tpcThis * (H / 128), 512, 0, stream>>>(
                (u16*)(ws + h_o), (u16*)(ws + w2b_o), offsets, tileOff,
                (u16*)(ws + y_o), cstart, tpcThis);
    }
    combine_kernel<<<T, 256, 0, stream>>>((u16*)(ws + y_o), (int*)(ws + inv_o), out);
}